// Round 15
// baseline (241.039 us; speedup 1.0000x reference)
//
#include <hip/hip_runtime.h>
#include <hip/hip_bf16.h>

// BlocksCore forward. Round 15: gates v4 = R11's verified dbuf structure
// (256-row tile, 512 threads, 2x64KB LDS dbuf) with T4 counted-vmcnt sync:
// raw s_barrier + s_waitcnt vmcnt(8) so prefetch loads stay in flight across
// the barrier (R11 used __syncthreads = vmcnt(0) drain; per m218 the counted
// wait IS the pipelining gain). Everything else identical to R14.

#define B_SZ 4096
#define NINP 512
#define NHID 2048
#define NB 8
#define BSZ 256
#define ATT_OUT 1024

typedef __attribute__((ext_vector_type(8))) short bf16x8;
typedef __attribute__((ext_vector_type(8))) unsigned short u16x8;
typedef __attribute__((ext_vector_type(4))) float f32x4;

__device__ __forceinline__ float sigf(float x) { return 1.0f / (1.0f + expf(-x)); }

__device__ __forceinline__ unsigned short f2bf(float x) {
    unsigned u = __float_as_uint(x);
    unsigned r = (u + 0x7fff + ((u >> 16) & 1)) >> 16;
    return (unsigned short)r;
}
__device__ __forceinline__ float bf2f(unsigned short u) {
    return __uint_as_float((unsigned)u << 16);
}

// async global->LDS, 16B per lane. LDS dest must be wave-uniform base + lane*16.
__device__ __forceinline__ void gload16(const void* g, void* l) {
    __builtin_amdgcn_global_load_lds(
        (const __attribute__((address_space(1))) unsigned int*)(unsigned long long)g,
        (__attribute__((address_space(3))) unsigned int*)(unsigned int)(unsigned long long)l,
        16, 0, 0);
}

__device__ __forceinline__ u16x8 cvt8(const float4& a, const float4& b) {
    u16x8 v;
    v[0] = f2bf(a.x); v[1] = f2bf(a.y); v[2] = f2bf(a.z); v[3] = f2bf(a.w);
    v[4] = f2bf(b.x); v[5] = f2bf(b.y); v[6] = f2bf(b.z); v[7] = f2bf(b.w);
    return v;
}

// ---------------------------------------------------------------------------
// prep1: fused elementwise prep
// blocks: [0,128) wgf pack | [128,4224) hx->bf16 | [4224,5248) inp->bf16 |
//         [5248,5504) Wv1->bf16 | [5504,7040) qkv-weight pack
// ---------------------------------------------------------------------------
__global__ __launch_bounds__(256) void prep1_kernel(
    const float* __restrict__ gw, const float* __restrict__ fw,
    unsigned short* __restrict__ Wgfb,
    const float4* __restrict__ hx4, u16x8* __restrict__ hxb8,
    const float4* __restrict__ inp4, u16x8* __restrict__ inpb8,
    const float4* __restrict__ Wv4, u16x8* __restrict__ Wvb8,
    const float* __restrict__ Wq, const float* __restrict__ Wk,
    const float* __restrict__ Wv, unsigned short* __restrict__ Wqkvb)
{
    const int bid = blockIdx.x;
    if (bid < 128) {
        int t = bid * 256 + threadIdx.x;
        Wgfb[t] = f2bf((t < 16384) ? gw[t] : fw[t - 16384]);
    } else if (bid < 4224) {
        long i = (long)(bid - 128) * 256 + threadIdx.x;
        hxb8[i] = cvt8(hx4[i * 2], hx4[i * 2 + 1]);
    } else if (bid < 5248) {
        long i = (long)(bid - 4224) * 256 + threadIdx.x;
        inpb8[i] = cvt8(inp4[i * 2], inp4[i * 2 + 1]);
    } else if (bid < 5504) {
        long i = (long)(bid - 5248) * 256 + threadIdx.x;
        Wvb8[i] = cvt8(Wv4[i * 2], Wv4[i * 2 + 1]);
    } else {
        int idx = (bid - 5504) * 256 + threadIdx.x;   // 0..393215
        int k = idx & 255;
        int n = (idx >> 8) % 192;
        int kb = idx / (192 * 256);
        const float* src = (n < 64) ? Wq : (n < 128) ? Wk : Wv;
        int nn = n & 63;
        Wqkvb[idx] = f2bf(src[(long)kb * 16384 + k * 64 + nn]);
    }
}

// ---------------------------------------------------------------------------
// prepW: fused Wih + Whh f32 -> bf16.
// ---------------------------------------------------------------------------
__global__ __launch_bounds__(256) void prepW_kernel(
    const float4* __restrict__ Wih4, u16x8* __restrict__ Wihb8,
    const float4* __restrict__ Whh4, u16x8* __restrict__ Whhb8)
{
    const int bid = blockIdx.x;
    if (bid < 4096) {
        long i = (long)bid * 256 + threadIdx.x;
        Wihb8[i] = cvt8(Wih4[i * 2], Wih4[i * 2 + 1]);
    } else {
        long i = (long)(bid - 4096) * 256 + threadIdx.x;
        Whhb8[i] = cvt8(Whh4[i * 2], Whh4[i * 2 + 1]);
    }
}

// ---------------------------------------------------------------------------
// Fused f32 GEMMs for the mask-critical path (R5-proven config, 1152 blocks).
// Ascending-k scalar accumulation: rank-stable s1 (mask-safe).
// ---------------------------------------------------------------------------
__global__ __launch_bounds__(256) void qk1_kernel(
    const float* __restrict__ inp, const float* __restrict__ hx,
    const float* __restrict__ Wk1, const float* __restrict__ Wq,
    float* __restrict__ k1, float* __restrict__ q)
{
    const int role = blockIdx.y;
    const int m0 = blockIdx.x * 32;
    const float* A; long lda; const float* Bw; int K; float* C; int ldc;
    if (role == 8) {
        A = inp + (long)m0 * 512; lda = 512; Bw = Wk1; K = 512;
        C = k1 + (long)m0 * 64; ldc = 64;
    } else {
        A = hx + (long)m0 * 2048 + role * 256; lda = 2048;
        Bw = Wq + (long)role * 256 * 64; K = 256;
        C = q + (long)m0 * 512 + role * 64; ldc = 512;
    }

    __shared__ float As[32][33];
    __shared__ float Bs[32][64];

    const int t = threadIdx.x;
    const int ty = t >> 4;
    const int tx = t & 15;

    float acc[2][4] = {};

    for (int k0 = 0; k0 < K; k0 += 32) {
        {
            int m = t >> 3, kk = (t & 7) << 2;
            float4 av = *reinterpret_cast<const float4*>(&A[(long)m * lda + k0 + kk]);
            As[m][kk] = av.x; As[m][kk + 1] = av.y;
            As[m][kk + 2] = av.z; As[m][kk + 3] = av.w;
        }
        #pragma unroll
        for (int u = 0; u < 2; ++u) {
            int f = t + 256 * u;
            int kr = f >> 4, c = (f & 15) << 2;
            float4 bv = *reinterpret_cast<const float4*>(&Bw[(long)(k0 + kr) * 64 + c]);
            *reinterpret_cast<float4*>(&Bs[kr][c]) = bv;
        }
        __syncthreads();
        #pragma unroll
        for (int kk = 0; kk < 32; ++kk) {
            float a0 = As[ty * 2][kk];
            float a1 = As[ty * 2 + 1][kk];
            float4 bv = *reinterpret_cast<const float4*>(&Bs[kk][tx * 4]);
            acc[0][0] += a0 * bv.x; acc[0][1] += a0 * bv.y;
            acc[0][2] += a0 * bv.z; acc[0][3] += a0 * bv.w;
            acc[1][0] += a1 * bv.x; acc[1][1] += a1 * bv.y;
            acc[1][2] += a1 * bv.z; acc[1][3] += a1 * bv.w;
        }
        __syncthreads();
    }
    #pragma unroll
    for (int i = 0; i < 2; ++i) {
        float4 v = {acc[i][0], acc[i][1], acc[i][2], acc[i][3]};
        *reinterpret_cast<float4*>(&C[(long)(ty * 2 + i) * ldc + tx * 4]) = v;
    }
}

// ---------------------------------------------------------------------------
// Generic bf16 MFMA GEMM: C[m,n] = sum_k A[m,k] * B[n,k]  (B is N x K).
// ---------------------------------------------------------------------------
__global__ __launch_bounds__(256, 2) void gemm_mfma_bf(
    const unsigned short* __restrict__ A,
    const unsigned short* __restrict__ Bm,
    unsigned short* __restrict__ Cv,
    int K, int lda, int ldb, int ldc,
    long aOffZ, long bOffZ, long cOffZ)
{
    const int m0 = blockIdx.x * 128;
    const int n0 = blockIdx.y * 64;
    const int z = blockIdx.z;
    A += (long)z * aOffZ;
    Bm += (long)z * bOffZ;

    __shared__ unsigned short As[128 * 64];
    __shared__ unsigned short Bs[64 * 64];

    const int t = threadIdx.x;
    const int wid = t >> 6;
    const int l = t & 63;
    const int l15 = l & 15;
    const int l4 = l >> 4;
    const int wm = wid >> 1;
    const int wn = wid & 1;

    f32x4 acc[4][2];
    #pragma unroll
    for (int m = 0; m < 4; ++m)
        #pragma unroll
        for (int n = 0; n < 2; ++n)
            acc[m][n] = (f32x4){0.f, 0.f, 0.f, 0.f};

    for (int k0 = 0; k0 < K; k0 += 64) {
        #pragma unroll
        for (int s = 0; s < 4; ++s) {
            int ci = (wid * 4 + s) * 64 + l;
            int r = ci >> 3, cs = ci & 7;
            gload16(A + (long)(m0 + r) * lda + k0 + ((cs ^ (r & 7)) << 3), &As[ci * 8]);
        }
        #pragma unroll
        for (int s = 0; s < 2; ++s) {
            int ci = (wid * 2 + s) * 64 + l;
            int rn = ci >> 3, cs = ci & 7;
            gload16(Bm + (long)(n0 + rn) * ldb + k0 + ((cs ^ (rn & 7)) << 3), &Bs[ci * 8]);
        }
        __syncthreads();
        #pragma unroll
        for (int kh = 0; kh < 2; ++kh) {
            bf16x8 af[4];
            #pragma unroll
            for (int m = 0; m < 4; ++m) {
                int r = wm * 64 + m * 16 + l15;
                int c = kh * 4 + l4;
                af[m] = *reinterpret_cast<const bf16x8*>(&As[r * 64 + ((c ^ (r & 7)) << 3)]);
            }
            #pragma unroll
            for (int nf = 0; nf < 2; ++nf) {
                int rn = wn * 32 + nf * 16 + l15;
                int c = kh * 4 + l4;
                bf16x8 bf = *reinterpret_cast<const bf16x8*>(
                    &Bs[rn * 64 + ((c ^ (rn & 7)) << 3)]);
                #pragma unroll
                for (int m = 0; m < 4; ++m)
                    acc[m][nf] = __builtin_amdgcn_mfma_f32_16x16x32_bf16(
                        af[m], bf, acc[m][nf], 0, 0, 0);
            }
        }
        __syncthreads();
    }

    #pragma unroll
    for (int nf = 0; nf < 2; ++nf) {
        const int ccol = n0 + wn * 32 + nf * 16 + l15;
        #pragma unroll
        for (int m = 0; m < 4; ++m) {
            #pragma unroll
            for (int r = 0; r < 4; ++r) {
                const long crow = m0 + wm * 64 + m * 16 + l4 * 4 + r;
                Cv[(long)z * cOffZ + crow * ldc + ccol] = f2bf(acc[m][nf][r]);
            }
        }
    }
}

// ---------------------------------------------------------------------------
// s1 / sigmoid weight / exact top-k mask (f32, mask-critical).
// ---------------------------------------------------------------------------
__global__ __launch_bounds__(256) void s1_mask_kernel(
    const float* __restrict__ q, const float* __restrict__ k1,
    float* __restrict__ w_ws, float* __restrict__ mblk,
    float* __restrict__ mask_out)
{
    const int wave = threadIdx.x >> 6;
    const int lane = threadIdx.x & 63;
    const int b = blockIdx.x * 4 + wave;

    float p[8];
    const float kv = k1[(long)b * 64 + lane];
    #pragma unroll
    for (int kb = 0; kb < 8; ++kb)
        p[kb] = q[(long)b * 512 + kb * 64 + lane] * kv;

    #pragma unroll
    for (int off = 1; off < 64; off <<= 1) {
        #pragma unroll
        for (int kb = 0; kb < 8; ++kb) p[kb] += __shfl_xor(p[kb], off);
    }

    float s[8], mv[8];
    #pragma unroll
    for (int kb = 0; kb < 8; ++kb) s[kb] = p[kb] * 0.125f;

    #pragma unroll
    for (int j = 0; j < 8; ++j) {
        int r = 0;
        #pragma unroll
        for (int i = 0; i < 8; ++i)
            r += (s[i] < s[j]) || (s[i] == s[j] && i < j);
        mv[j] = (r >= 4) ? 1.0f : 0.0f;
    }
    if (lane < 8) {
        w_ws[(long)b * 8 + lane] = sigf(s[lane]);
        mblk[(long)b * 8 + lane] = mv[lane];
    }
    #pragma unroll
    for (int it = 0; it < 8; ++it) {
        const float mvv = mv[it];
        float4 v = {mvv, mvv, mvv, mvv};
        *reinterpret_cast<float4*>(&mask_out[(long)b * 2048 + it * 256 + lane * 4]) = v;
    }
}

// ---------------------------------------------------------------------------
// MFMA gates + LSTM v4: R11's verified 256-row/512-thread dbuf structure with
// counted-vmcnt sync (T4). Per K-step:
//   stage(t+1, buf^1)                       // 8 gload16/thread
//   s_waitcnt vmcnt(8)                      // stage(t) done; t+1 in flight
//   s_barrier                               // buf[t] visible everywhere
//   compute(buf)                            // ds_read + MFMA (lgkm by compiler)
//   s_barrier                               // all done reading buf before t+2 lands
// LDS 130 KB (1 block/CU, 8 waves). acc[4][8] per wave as R10/R11.
// ---------------------------------------------------------------------------
__global__ __launch_bounds__(512, 1) void gates_mfma_kernel(
    const unsigned short* __restrict__ Ib,   // inpb [4096][512]
    const unsigned short* __restrict__ Hb,   // hxb  [4096][2048]
    const unsigned short* __restrict__ Gt,   // [8][1024][512]
    const unsigned short* __restrict__ Whhb, // [8][1024][256]
    const float* __restrict__ b_ih, const float* __restrict__ b_hh,
    const float* __restrict__ w_ws, const float* __restrict__ mblk,
    const float* __restrict__ cx,
    float* __restrict__ c_out,
    unsigned short* __restrict__ hn_b)
{
    // XCD swizzle: grid (16,4,8), linear n -> XCD n%8 owns kb=n%8;
    // within XCD j0 varies fastest. Bijective over 512 works.
    const int n = blockIdx.x + 16 * blockIdx.y + 64 * blockIdx.z;
    const int w = (n & 7) * 64 + (n >> 3);
    const int m0 = ((w >> 2) & 15) * 256;
    const int j0 = (w & 3) * 64;
    const int kb = w >> 6;

    __shared__ unsigned short Asm[2][256 * 64];   // 2 x 32 KB
    __shared__ unsigned short Bsm[2][256 * 64];   // 2 x 32 KB
    __shared__ float wv[256];
    __shared__ float mbs[256];

    const int t = threadIdx.x;
    const int wid = t >> 6;        // 0..7
    const int l = t & 63;
    const int l15 = l & 15;
    const int l4 = l >> 4;
    const int wm = wid >> 1;       // 0..3 (64 rows each)
    const int wj = wid & 1;        // 0..1 (32 j each)

    if (t < 256) {
        wv[t] = w_ws[(long)(m0 + t) * 8 + kb];
        mbs[t] = mblk[(long)(m0 + t) * 8 + kb];
    }

    f32x4 acc[4][8];
    #pragma unroll
    for (int m = 0; m < 4; ++m)
        #pragma unroll
        for (int nn = 0; nn < 8; ++nn)
            acc[m][nn] = (f32x4){0.f, 0.f, 0.f, 0.f};

    // stage K-step `step` into buffer `buf`: A 2048 chunks, B 2048; 4+4/thread.
    auto stage = [&](int step, int buf) {
        const unsigned short* Aptr; long lda;
        const unsigned short* Bptr; long ldb; int k0;
        if (step < 8) {
            Aptr = Ib + (long)m0 * 512; lda = 512;
            Bptr = Gt + (long)kb * 1024 * 512; ldb = 512;
            k0 = step * 64;
        } else {
            Aptr = Hb + (long)m0 * 2048 + kb * 256; lda = 2048;
            Bptr = Whhb + (long)kb * 1024 * 256; ldb = 256;
            k0 = (step - 8) * 64;
        }
        unsigned short* Al = Asm[buf];
        unsigned short* Bl = Bsm[buf];
        #pragma unroll
        for (int s = 0; s < 4; ++s) {
            int ci = wid * 256 + s * 64 + l;
            int r = ci >> 3, cs = ci & 7;
            gload16(Aptr + (long)r * lda + k0 + ((cs ^ (r & 7)) << 3), &Al[ci * 8]);
        }
        #pragma unroll
        for (int s = 0; s < 4; ++s) {
            int ci = wid * 256 + s * 64 + l;
            int rn = ci >> 3, cs = ci & 7;
            int sg = rn >> 6, jl = rn & 63;
            gload16(Bptr + (long)(sg * 256 + j0 + jl) * ldb + k0 + ((cs ^ (rn & 7)) << 3),
                    &Bl[ci * 8]);
        }
    };

    auto compute = [&](int buf) {
        const unsigned short* Al = Asm[buf];
        const unsigned short* Bl = Bsm[buf];
        #pragma unroll
        for (int kh = 0; kh < 2; ++kh) {
            bf16x8 af[4];
            #pragma unroll
            for (int m = 0; m < 4; ++m) {
                int r = wm * 64 + m * 16 + l15;
                int c = kh * 4 + l4;
                af[m] = *reinterpret_cast<const bf16x8*>(&Al[r * 64 + ((c ^ (r & 7)) << 3)]);
            }
            #pragma unroll
            for (int sg = 0; sg < 4; ++sg) {
                #pragma unroll
                for (int jf = 0; jf < 2; ++jf) {
                    int rn = sg * 64 + wj * 32 + jf * 16 + l15;
                    int c = kh * 4 + l4;
                    bf16x8 bf = *reinterpret_cast<const bf16x8*>(
                        &Bl[rn * 64 + ((c ^ (rn & 7)) << 3)]);
                    #pragma unroll
                    for (int m = 0; m < 4; ++m)
                        acc[m][sg * 2 + jf] = __builtin_amdgcn_mfma_f32_16x16x32_bf16(
                            af[m], bf, acc[m][sg * 2 + jf], 0, 0, 0);
                }
            }
        }
    };

    // 12 K-steps: 0..7 phase-1 (inp @ G^T, K=512), 8..11 phase-2 (hx @ Whh^T).
    stage(0, 0);
    asm volatile("s_waitcnt vmcnt(0) lgkmcnt(0)" ::: "memory");
    __builtin_amdgcn_s_barrier();            // buf0 + wv/mbs ready everywhere
    int cur = 0;
    for (int step = 0; step < 12; ++step) {
        if (step < 11) {
            stage(step + 1, cur ^ 1);        // issue prefetch (8 loads/thread)
            asm volatile("s_waitcnt vmcnt(8)" ::: "memory");  // stage(step) done
        } else {
            asm volatile("s_waitcnt vmcnt(0)" ::: "memory");
        }
        __builtin_amdgcn_sched_barrier(0);
        __builtin_amdgcn_s_barrier();        // buf[step] visible in all waves
        compute(cur);
        if (step == 7) {
            float wsc[4][4];
            #pragma unroll
            for (int m = 0; m < 4; ++m)
                #pragma unroll
                for (int r = 0; r < 4; ++r)
                    wsc[m][r] = wv[wm * 64 + m * 16 + l4 * 4 + r];
            #pragma unroll
            for (int m = 0; m < 4; ++m)
                #pragma unroll
                for (int nn = 0; nn < 8; ++nn)
                    #pragma unroll
                    for (int r = 0; r < 4; ++r)
                        acc[m][nn][r] *= wsc[m][r];
        }
        __builtin_amdgcn_s_barrier();        // all waves done reading buf[step]
        cur ^= 1;
    }

    #pragma unroll
    for (int jf = 0; jf < 2; ++jf) {
        const int jcol = j0 + wj * 32 + jf * 16 + l15;
        const long bb = (long)kb * 1024 + jcol;
        const float bI = b_ih[bb] + b_hh[bb];
        const float bF = b_ih[bb + 256] + b_hh[bb + 256];
        const float bG = b_ih[bb + 512] + b_hh[bb + 512];
        const float bO = b_ih[bb + 768] + b_hh[bb + 768];
        #pragma unroll
        for (int m = 0; m < 4; ++m) {
            #pragma unroll
            for (int r = 0; r < 4; ++r) {
                const long row = m0 + wm * 64 + m * 16 + l4 * 4 + r;
                const long idx = row * 2048 + kb * 256 + jcol;
                const float mv = mbs[wm * 64 + m * 16 + l4 * 4 + r];
                const float ig = acc[m][0 + jf][r] + bI;
                const float fg = acc[m][2 + jf][r] + bF;
                const float gg = acc[m][4 + jf][r] + bG;
                const float og = acc[m][6 + jf][r] + bO;
                const float co = cx[idx];
                const float cn = sigf(fg) * co + sigf(ig) * tanhf(gg);
                const float hn = sigf(og) * tanhf(cn);
                c_out[idx] = (mv != 0.0f) ? cn : co;
                hn_b[idx] = f2bf(hn);
            }
        }
    }
}

// ---------------------------------------------------------------------------
// Inner NBxNB attention over bf16 qkv [4096][1536]; vectorized u16x8 loads.
// ---------------------------------------------------------------------------
__global__ __launch_bounds__(256) void attn_m2_kernel(
    const unsigned short* __restrict__ qkv, unsigned short* __restrict__ ob)
{
    const int tid = blockIdx.x * 256 + threadIdx.x;
    const int b = tid >> 5;
    const int qkb = (tid >> 2) & 7;
    const int h = tid & 3;
    const u16x8* base8 = reinterpret_cast<const u16x8*>(qkv + (long)b * 1536);

    float qv[16];
    {
        u16x8 q0 = base8[qkb * 24 + h * 2];
        u16x8 q1 = base8[qkb * 24 + h * 2 + 1];
        #pragma unroll
        for (int e = 0; e < 8; ++e) { qv[e] = bf2f(q0[e]); qv[8 + e] = bf2f(q1[e]); }
    }

    float sc[8];
    float mx = -1e30f;
    #pragma unroll
    for (int kk = 0; kk < 8; ++kk) {
        u16x8 k0 = base8[kk * 24 + 8 + h * 2];
        u16x8 k1 = base8[kk * 24 + 9 + h * 2];
        float s = 0.f;
        #pragma unroll
        for (int e = 0; e < 8; ++e)
            s += qv[e] * bf2f(k0[e]) + qv[8 + e] * bf2f(k1[e]);
        s *= 0.25f;
        sc[kk] = s;
        mx = fmaxf(mx, s);
    }
    float den = 0.f;
    #pragma unroll
    for (int kk = 0; kk < 8; ++kk) { sc[kk] = expf(sc[kk] - mx); den += sc[kk]; }
    const float inv = 1.0f / den;

    float ov[16] = {};
    #pragma unroll
    for (int kk = 0; kk < 8; ++kk) {
        const float pw = sc[kk] * inv;
        u16x8 v0 = base8[kk * 24 + 16 + h * 2];
        u16x8 v1 = base8[kk * 24 + 17 + h * 2];
        #pragma unroll
        for (int e = 0; e < 8; ++e) {
            ov[e] += pw * bf2f(v0[e]);
            ov[8 + e] += pw * bf2f(v1[e]);
        }
    }
    u16x8 r0, r1;
    #pragma unroll
    for (int e = 0; e < 8; ++e) { r0[e] = f2bf(ov[e]); r1[e] = f2bf(ov[e + 8]); }
    unsigned short* op = ob + (long)((b * 8 + qkb) * 64 + h * 16);
    *reinterpret_cast<u16x8*>(op) = r0;
    *reinterpret_cast<u16x8*>(op + 8) = r1;
}

// ---------------------------------------------------------------------------
// MFMA attn-final: g = O@gate_w^T, f = O@fc_w^T (K=64), att = sig(g)*tanh(f).
// h_final = bf2f(hnb) + att; masked blend vs hx. h_out is pure-write.
// ---------------------------------------------------------------------------
__global__ __launch_bounds__(256) void attn_final_kernel(
    const unsigned short* __restrict__ ob,   // [32768][64]
    const unsigned short* __restrict__ Wgfb, // [512][64]: 0-255 gate, 256-511 fc
    const float* __restrict__ gate_b, const float* __restrict__ fc_b,
    const float* __restrict__ mblk,
    const float* __restrict__ hx,
    const unsigned short* __restrict__ hnb,  // bf16 h_new [4096][2048]
    float* __restrict__ h_out)
{
    const int m0 = blockIdx.x * 128;
    const int j0 = blockIdx.y * 64;

    __shared__ unsigned short As[128 * 64];
    __shared__ unsigned short Bs[128 * 64];

    const int t = threadIdx.x;
    const int wid = t >> 6;
    const int l = t & 63;
    const int l15 = l & 15;
    const int l4 = l >> 4;
    const int wm = wid >> 1;
    const int wn = wid & 1;

    #pragma unroll
    for (int s = 0; s < 4; ++s) {
        int ci = (wid * 4 + s) * 64 + l;
        int r = ci >> 3, cs = ci & 7;
        gload16(ob + (long)(m0 + r) * 64 + ((cs ^ (r & 7)) << 3), &As[ci * 8]);
    }
    #pragma unroll
    for (int s = 0; s < 4; ++s) {
        int ci = (wid * 4 + s) * 64 + l;
        int r = ci >> 3, cs = ci & 7;
        int n = (r < 64) ? (j0 + r) : (256 + j0 + (r - 64));
        gload16(Wgfb + (long)n * 64 + ((cs ^ (r & 7)) << 3), &Bs[ci * 8]);
    }
    __syncthreads();

    f32x4 acc[4][2][2];
    #pragma unroll
    for (int m = 0; m < 4; ++m)
        #pragma unroll
        for (int nf = 0; nf < 2; ++nf)
            #pragma unroll
            for (int gf = 0; gf < 2; ++gf)
                acc[m][nf][gf] = (f32x4){0.f, 0.f, 0.f, 0.f};

    #pragma unroll
    for (int kh = 0; kh < 2; ++kh) {
        const int c = kh * 4 + l4;
        bf16x8 af[4];
        #pragma unroll
        for (int m = 0; m < 4; ++m) {
            int r = wm * 64 + m * 16 + l15;
            af[m] = *reinterpret_cast<const bf16x8*>(&As[r * 64 + ((c ^ (r & 7)) << 3)]);
        }
        #pragma unroll
        for (int nf = 0; nf < 2; ++nf) {
            int rg = wn * 32 + nf * 16 + l15;
            bf16x8 bg = *reinterpret_cast<const bf16x8*>(
                &Bs[rg * 64 + ((c ^ (rg & 7)) << 3)]);
            int rf = 64 + rg;
            bf16x8 bfv = *reinterpret_cast<const bf16x8*>(
                &Bs[rf * 64 + ((c ^ (rf & 7)) << 3)]);
            #pragma unroll
            for (int m = 0; m < 4; ++m) {
                acc[m][nf][0] = __builtin_amdgcn_mfma_f32_16x16x32_bf16(
                    af[m], bg, acc[m][nf][0], 0, 0, 0);
                acc[m][nf][1] = __builtin_amdgcn_mfma_f32_16x16x32_bf16(
                    af[m], bfv, acc[m][nf][1], 0, 0, 0);
            }
        }
    }

    #pragma unroll
    for (int nf = 0; nf < 2; ++nf) {
        const int j = j0 + wn * 32 + nf * 16 + l15;
        const float gb = gate_b[j];
        const float fb = fc_b[j];
        #pragma unroll
        for (int m = 0; m < 4; ++m) {
            #pragma unroll
            for (int r = 0; r < 4; ++r) {
                const long p = m0 + wm * 64 + m * 16 + l4 * 4 + r;
                const float g = acc[m][nf][0][r] + gb;
                const float f = acc[m][nf][1][r] + fb;
                const float att = sigf(g) * tanhf(f);
                const long idx = (p >> 3) * 2048 + (p & 7) * 256 + j;
                const float mv = mblk[p];
                const float hn = bf2f(hnb[idx]) + att;
                h_out[idx] = (mv != 0.0f) ? hn : hx[idx];
            }
        }
    }
}

// ---------------------------------------------------------------------------
extern "C" void kernel_launch(void* const* d_in, const int* in_sizes, int n_in,
                              void* d_out, int out_size, void* d_ws, size_t ws_size,
                              hipStream_t stream) {
    const float* inp    = (const float*)d_in[0];
    const float* hx     = (const float*)d_in[1];
    const float* cx     = (const float*)d_in[2];
    const float* Wq_i   = (const float*)d_in[3];
    const float* Wk_i   = (const float*)d_in[4];
    const float* Wv_i   = (const float*)d_in[5];
    const float* Wq_m   = (const float*)d_in[6];
    const float* Wk_m   = (const float*)d_in[7];
    const float* Wv_m   = (const float*)d_in[8];
    const float* fc_w   = (const float*)d_in[9];
    const float* fc_b   = (const float*)d_in[10];
    const float* gate_w = (const float*)d_in[11];
    const float* gate_b = (const float*)d_in[12];
    const float* Wih    = (const float*)d_in[13];
    const float* Whh    = (const float*)d_in[14];
    const float* b_ih   = (const float*)d_in[15];
    const float* b_hh   = (const float*)d_in[16];

    float* out      = (float*)d_out;
    float* h_out    = out;
    float* c_out    = out + (long)B_SZ * 2048;
    float* mask_out = out + (long)2 * B_SZ * 2048;

    // ---- workspace layout with lifetime aliasing (~61.1 MB) ----
    float* ws   = (float*)d_ws;
    float* w_ws = ws;                                       // B*8 f32
    float* mblk = w_ws + (long)B_SZ * 8;                    // B*8 f32
    unsigned short* Gt  = (unsigned short*)(mblk + (long)B_SZ * 8);  // 8*1024*512
    unsigned short* hxb = Gt + (long)8 * 1024 * 512;                 // B*2048
    unsigned short* hnb  = hxb + (long)B_SZ * 2048;         // B*2048 (gates -> final)
    unsigned short* Wihb = hnb + (long)B_SZ * 2048;         // 8M u16 (prepW -> G-gemm)
    unsigned short* Whhb = Wihb + (long)8 * 1024 * 1024;    // 2M u16 (prepW -> gates)
    unsigned short* Wgfb = Whhb + (long)8 * 1024 * 256;     // 512*64 u16
    unsigned short* Wqkvb = Wgfb + 512 * 64;                // 8*192*256 u16 (own slot)
    // early aliases inside Wihb span (dead before prepW):
    float* k1 = (float*)Wihb;                               // B*64 f32
    float* q  = k1 + (long)B_SZ * 64;                       // B*512 f32
    // Wvb: prep1 -> G-gemm; lives in hnb span (hnb written later by gates)
    unsigned short* Wvb = hnb;                              // 512*1024 bf16
    // inpb: prep1 -> gates; lives in d_out h region (attn_final overwrites all)
    unsigned short* inpb = (unsigned short*)h_out;          // B*512 bf16
    // late aliases (after gates):
    unsigned short* qkvb  = hxb;                            // B*1536 (over dead hxb)
    unsigned short* ob    = (unsigned short*)Gt;            // 32768*64 (over dead Gt)

    // fused prep: wgf | hx->bf16 | inp->bf16 | Wv1->bf16 | qkv-weight pack
    prep1_kernel<<<dim3(7040), 256, 0, stream>>>(
        gate_w, fc_w, Wgfb,
        (const float4*)hx, (u16x8*)hxb,
        (const float4*)inp, (u16x8*)inpb,
        (const float4*)(Wv_i + (long)NINP * ATT_OUT), (u16x8*)Wvb,
        Wq_m, Wk_m, Wv_m, Wqkvb);
    // k1 + q (f32, mask-critical)
    qk1_kernel<<<dim3(128, 9), 256, 0, stream>>>(
        inp, hx, Wk_i + (long)NINP * 64, Wq_i, k1, q);
    // s1, w, mblk, mask (kills k1,q)
    s1_mask_kernel<<<dim3(B_SZ / 4), 256, 0, stream>>>(q, k1, w_ws, mblk, mask_out);
    // fused Wih+Whh -> bf16 (clobbers k1/q aliases — dead)
    prepW_kernel<<<dim3(5120), 256, 0, stream>>>(
        (const float4*)Wih, (u16x8*)Wihb, (const float4*)Whh, (u16x8*)Whhb);
    // G[kb] = Wih[kb] @ Wv1^T  -> Gt [8][1024][512] bf16
    gemm_mfma_bf<<<dim3(8, 8, 8), 256, 0, stream>>>(
        Wihb, Wvb, Gt, 1024, 1024, 1024, 512,
        (long)1024 * 1024, 0, (long)1024 * 512);
    // gates + LSTM v4 (256-tile dbuf, counted-vmcnt sync, XCD-swizzled)
    gates_mfma_kernel<<<dim3(16, 4, 8), 512, 0, stream>>>(
        inpb, hxb, Gt, Whhb, b_ih, b_hh, w_ws, mblk, cx, c_out, hnb);
    // qkv = h_new_block @ W*_m (batched MFMA) -> bf16
    gemm_mfma_bf<<<dim3(32, 3, 8), 256, 0, stream>>>(
        hnb, Wqkvb, qkvb, 256, 2048, 256, 1536, 256, (long)192 * 256, 192);
    // inner attention -> ob (bf16)
    attn_m2_kernel<<<dim3(B_SZ * 32 / 256), 256, 0, stream>>>(qkvb, ob);
    // MFMA epilogue: att + h rebuild/blend (pure-write h_out, clobbers inpb)
    attn_final_kernel<<<dim3(256, 4), 256, 0, stream>>>(
        ob, Wgfb, gate_b, fc_b, mblk, hx, hnb, h_out);
}

// Round 16
// 234.936 us; speedup vs baseline: 1.0260x; 1.0260x over previous
//
#include <hip/hip_runtime.h>
#include <hip/hip_bf16.h>

// BlocksCore forward. Round 16: restore R14 (best verified, 236.5 µs; R10-
// equivalent config). Gates schedule ledger closed: R6/R11/R12/R13/R15 all
// regress or null vs the R10 2-barrier 128x256j (256,2) config. Tail at
// memory floors. 15.4x vs round-1 baseline.

#define B_SZ 4096
#define NINP 512
#define NHID 2048
#define NB 8
#define BSZ 256
#define ATT_OUT 1024

typedef __attribute__((ext_vector_type(8))) short bf16x8;
typedef __attribute__((ext_vector_type(8))) unsigned short u16x8;
typedef __attribute__((ext_vector_type(4))) float f32x4;

__device__ __forceinline__ float sigf(float x) { return 1.0f / (1.0f + expf(-x)); }

__device__ __forceinline__ unsigned short f2bf(float x) {
    unsigned u = __float_as_uint(x);
    unsigned r = (u + 0x7fff + ((u >> 16) & 1)) >> 16;
    return (unsigned short)r;
}
__device__ __forceinline__ float bf2f(unsigned short u) {
    return __uint_as_float((unsigned)u << 16);
}

// async global->LDS, 16B per lane. LDS dest must be wave-uniform base + lane*16.
__device__ __forceinline__ void gload16(const void* g, void* l) {
    __builtin_amdgcn_global_load_lds(
        (const __attribute__((address_space(1))) unsigned int*)(unsigned long long)g,
        (__attribute__((address_space(3))) unsigned int*)(unsigned int)(unsigned long long)l,
        16, 0, 0);
}

__device__ __forceinline__ u16x8 cvt8(const float4& a, const float4& b) {
    u16x8 v;
    v[0] = f2bf(a.x); v[1] = f2bf(a.y); v[2] = f2bf(a.z); v[3] = f2bf(a.w);
    v[4] = f2bf(b.x); v[5] = f2bf(b.y); v[6] = f2bf(b.z); v[7] = f2bf(b.w);
    return v;
}

// ---------------------------------------------------------------------------
// prep1: fused elementwise prep
// blocks: [0,128) wgf pack | [128,4224) hx->bf16 | [4224,5248) inp->bf16 |
//         [5248,5504) Wv1->bf16 | [5504,7040) qkv-weight pack
// ---------------------------------------------------------------------------
__global__ __launch_bounds__(256) void prep1_kernel(
    const float* __restrict__ gw, const float* __restrict__ fw,
    unsigned short* __restrict__ Wgfb,
    const float4* __restrict__ hx4, u16x8* __restrict__ hxb8,
    const float4* __restrict__ inp4, u16x8* __restrict__ inpb8,
    const float4* __restrict__ Wv4, u16x8* __restrict__ Wvb8,
    const float* __restrict__ Wq, const float* __restrict__ Wk,
    const float* __restrict__ Wv, unsigned short* __restrict__ Wqkvb)
{
    const int bid = blockIdx.x;
    if (bid < 128) {
        int t = bid * 256 + threadIdx.x;
        Wgfb[t] = f2bf((t < 16384) ? gw[t] : fw[t - 16384]);
    } else if (bid < 4224) {
        long i = (long)(bid - 128) * 256 + threadIdx.x;
        hxb8[i] = cvt8(hx4[i * 2], hx4[i * 2 + 1]);
    } else if (bid < 5248) {
        long i = (long)(bid - 4224) * 256 + threadIdx.x;
        inpb8[i] = cvt8(inp4[i * 2], inp4[i * 2 + 1]);
    } else if (bid < 5504) {
        long i = (long)(bid - 5248) * 256 + threadIdx.x;
        Wvb8[i] = cvt8(Wv4[i * 2], Wv4[i * 2 + 1]);
    } else {
        int idx = (bid - 5504) * 256 + threadIdx.x;   // 0..393215
        int k = idx & 255;
        int n = (idx >> 8) % 192;
        int kb = idx / (192 * 256);
        const float* src = (n < 64) ? Wq : (n < 128) ? Wk : Wv;
        int nn = n & 63;
        Wqkvb[idx] = f2bf(src[(long)kb * 16384 + k * 64 + nn]);
    }
}

// ---------------------------------------------------------------------------
// prepW: fused Wih + Whh f32 -> bf16.
// ---------------------------------------------------------------------------
__global__ __launch_bounds__(256) void prepW_kernel(
    const float4* __restrict__ Wih4, u16x8* __restrict__ Wihb8,
    const float4* __restrict__ Whh4, u16x8* __restrict__ Whhb8)
{
    const int bid = blockIdx.x;
    if (bid < 4096) {
        long i = (long)bid * 256 + threadIdx.x;
        Wihb8[i] = cvt8(Wih4[i * 2], Wih4[i * 2 + 1]);
    } else {
        long i = (long)(bid - 4096) * 256 + threadIdx.x;
        Whhb8[i] = cvt8(Whh4[i * 2], Whh4[i * 2 + 1]);
    }
}

// ---------------------------------------------------------------------------
// Fused f32 GEMMs for the mask-critical path (R5-proven config, 1152 blocks).
// Ascending-k scalar accumulation: rank-stable s1 (mask-safe).
// ---------------------------------------------------------------------------
__global__ __launch_bounds__(256) void qk1_kernel(
    const float* __restrict__ inp, const float* __restrict__ hx,
    const float* __restrict__ Wk1, const float* __restrict__ Wq,
    float* __restrict__ k1, float* __restrict__ q)
{
    const int role = blockIdx.y;
    const int m0 = blockIdx.x * 32;
    const float* A; long lda; const float* Bw; int K; float* C; int ldc;
    if (role == 8) {
        A = inp + (long)m0 * 512; lda = 512; Bw = Wk1; K = 512;
        C = k1 + (long)m0 * 64; ldc = 64;
    } else {
        A = hx + (long)m0 * 2048 + role * 256; lda = 2048;
        Bw = Wq + (long)role * 256 * 64; K = 256;
        C = q + (long)m0 * 512 + role * 64; ldc = 512;
    }

    __shared__ float As[32][33];
    __shared__ float Bs[32][64];

    const int t = threadIdx.x;
    const int ty = t >> 4;
    const int tx = t & 15;

    float acc[2][4] = {};

    for (int k0 = 0; k0 < K; k0 += 32) {
        {
            int m = t >> 3, kk = (t & 7) << 2;
            float4 av = *reinterpret_cast<const float4*>(&A[(long)m * lda + k0 + kk]);
            As[m][kk] = av.x; As[m][kk + 1] = av.y;
            As[m][kk + 2] = av.z; As[m][kk + 3] = av.w;
        }
        #pragma unroll
        for (int u = 0; u < 2; ++u) {
            int f = t + 256 * u;
            int kr = f >> 4, c = (f & 15) << 2;
            float4 bv = *reinterpret_cast<const float4*>(&Bw[(long)(k0 + kr) * 64 + c]);
            *reinterpret_cast<float4*>(&Bs[kr][c]) = bv;
        }
        __syncthreads();
        #pragma unroll
        for (int kk = 0; kk < 32; ++kk) {
            float a0 = As[ty * 2][kk];
            float a1 = As[ty * 2 + 1][kk];
            float4 bv = *reinterpret_cast<const float4*>(&Bs[kk][tx * 4]);
            acc[0][0] += a0 * bv.x; acc[0][1] += a0 * bv.y;
            acc[0][2] += a0 * bv.z; acc[0][3] += a0 * bv.w;
            acc[1][0] += a1 * bv.x; acc[1][1] += a1 * bv.y;
            acc[1][2] += a1 * bv.z; acc[1][3] += a1 * bv.w;
        }
        __syncthreads();
    }
    #pragma unroll
    for (int i = 0; i < 2; ++i) {
        float4 v = {acc[i][0], acc[i][1], acc[i][2], acc[i][3]};
        *reinterpret_cast<float4*>(&C[(long)(ty * 2 + i) * ldc + tx * 4]) = v;
    }
}

// ---------------------------------------------------------------------------
// Generic bf16 MFMA GEMM: C[m,n] = sum_k A[m,k] * B[n,k]  (B is N x K).
// ---------------------------------------------------------------------------
__global__ __launch_bounds__(256, 2) void gemm_mfma_bf(
    const unsigned short* __restrict__ A,
    const unsigned short* __restrict__ Bm,
    unsigned short* __restrict__ Cv,
    int K, int lda, int ldb, int ldc,
    long aOffZ, long bOffZ, long cOffZ)
{
    const int m0 = blockIdx.x * 128;
    const int n0 = blockIdx.y * 64;
    const int z = blockIdx.z;
    A += (long)z * aOffZ;
    Bm += (long)z * bOffZ;

    __shared__ unsigned short As[128 * 64];
    __shared__ unsigned short Bs[64 * 64];

    const int t = threadIdx.x;
    const int wid = t >> 6;
    const int l = t & 63;
    const int l15 = l & 15;
    const int l4 = l >> 4;
    const int wm = wid >> 1;
    const int wn = wid & 1;

    f32x4 acc[4][2];
    #pragma unroll
    for (int m = 0; m < 4; ++m)
        #pragma unroll
        for (int n = 0; n < 2; ++n)
            acc[m][n] = (f32x4){0.f, 0.f, 0.f, 0.f};

    for (int k0 = 0; k0 < K; k0 += 64) {
        #pragma unroll
        for (int s = 0; s < 4; ++s) {
            int ci = (wid * 4 + s) * 64 + l;
            int r = ci >> 3, cs = ci & 7;
            gload16(A + (long)(m0 + r) * lda + k0 + ((cs ^ (r & 7)) << 3), &As[ci * 8]);
        }
        #pragma unroll
        for (int s = 0; s < 2; ++s) {
            int ci = (wid * 2 + s) * 64 + l;
            int rn = ci >> 3, cs = ci & 7;
            gload16(Bm + (long)(n0 + rn) * ldb + k0 + ((cs ^ (rn & 7)) << 3), &Bs[ci * 8]);
        }
        __syncthreads();
        #pragma unroll
        for (int kh = 0; kh < 2; ++kh) {
            bf16x8 af[4];
            #pragma unroll
            for (int m = 0; m < 4; ++m) {
                int r = wm * 64 + m * 16 + l15;
                int c = kh * 4 + l4;
                af[m] = *reinterpret_cast<const bf16x8*>(&As[r * 64 + ((c ^ (r & 7)) << 3)]);
            }
            #pragma unroll
            for (int nf = 0; nf < 2; ++nf) {
                int rn = wn * 32 + nf * 16 + l15;
                int c = kh * 4 + l4;
                bf16x8 bf = *reinterpret_cast<const bf16x8*>(
                    &Bs[rn * 64 + ((c ^ (rn & 7)) << 3)]);
                #pragma unroll
                for (int m = 0; m < 4; ++m)
                    acc[m][nf] = __builtin_amdgcn_mfma_f32_16x16x32_bf16(
                        af[m], bf, acc[m][nf], 0, 0, 0);
            }
        }
        __syncthreads();
    }

    #pragma unroll
    for (int nf = 0; nf < 2; ++nf) {
        const int ccol = n0 + wn * 32 + nf * 16 + l15;
        #pragma unroll
        for (int m = 0; m < 4; ++m) {
            #pragma unroll
            for (int r = 0; r < 4; ++r) {
                const long crow = m0 + wm * 64 + m * 16 + l4 * 4 + r;
                Cv[(long)z * cOffZ + crow * ldc + ccol] = f2bf(acc[m][nf][r]);
            }
        }
    }
}

// ---------------------------------------------------------------------------
// s1 / sigmoid weight / exact top-k mask (f32, mask-critical).
// ---------------------------------------------------------------------------
__global__ __launch_bounds__(256) void s1_mask_kernel(
    const float* __restrict__ q, const float* __restrict__ k1,
    float* __restrict__ w_ws, float* __restrict__ mblk,
    float* __restrict__ mask_out)
{
    const int wave = threadIdx.x >> 6;
    const int lane = threadIdx.x & 63;
    const int b = blockIdx.x * 4 + wave;

    float p[8];
    const float kv = k1[(long)b * 64 + lane];
    #pragma unroll
    for (int kb = 0; kb < 8; ++kb)
        p[kb] = q[(long)b * 512 + kb * 64 + lane] * kv;

    #pragma unroll
    for (int off = 1; off < 64; off <<= 1) {
        #pragma unroll
        for (int kb = 0; kb < 8; ++kb) p[kb] += __shfl_xor(p[kb], off);
    }

    float s[8], mv[8];
    #pragma unroll
    for (int kb = 0; kb < 8; ++kb) s[kb] = p[kb] * 0.125f;

    #pragma unroll
    for (int j = 0; j < 8; ++j) {
        int r = 0;
        #pragma unroll
        for (int i = 0; i < 8; ++i)
            r += (s[i] < s[j]) || (s[i] == s[j] && i < j);
        mv[j] = (r >= 4) ? 1.0f : 0.0f;
    }
    if (lane < 8) {
        w_ws[(long)b * 8 + lane] = sigf(s[lane]);
        mblk[(long)b * 8 + lane] = mv[lane];
    }
    #pragma unroll
    for (int it = 0; it < 8; ++it) {
        const float mvv = mv[it];
        float4 v = {mvv, mvv, mvv, mvv};
        *reinterpret_cast<float4*>(&mask_out[(long)b * 2048 + it * 256 + lane * 4]) = v;
    }
}

// ---------------------------------------------------------------------------
// MFMA gates + LSTM (R10 local-optimum config: 128-row x 256-j tile,
// acc[4][8], (256,2)). Phase 1 K=512 (inp @ G^T), phase 2 K=256 (hx @ Whh^T),
// w-scale between. XCD-chunk swizzle (kb = XCD), j0 fastest for A L2 reuse.
// ---------------------------------------------------------------------------
__global__ __launch_bounds__(256, 2) void gates_mfma_kernel(
    const unsigned short* __restrict__ Ib,   // inpb [4096][512]
    const unsigned short* __restrict__ Hb,   // hxb  [4096][2048]
    const unsigned short* __restrict__ Gt,   // [8][1024][512]
    const unsigned short* __restrict__ Whhb, // [8][1024][256]
    const float* __restrict__ b_ih, const float* __restrict__ b_hh,
    const float* __restrict__ w_ws, const float* __restrict__ mblk,
    const float* __restrict__ cx,
    float* __restrict__ c_out,
    unsigned short* __restrict__ hn_b)
{
    const int n = blockIdx.x + 32 * blockIdx.y + 128 * blockIdx.z;
    const int w = (n & 7) * 128 + (n >> 3);
    const int m0 = ((w >> 2) & 31) * 128;
    const int j0 = (w & 3) * 64;
    const int kb = w >> 7;

    __shared__ unsigned short As[128 * 64];
    __shared__ unsigned short Bs[256 * 64];
    __shared__ float wv[128];
    __shared__ float mbs[128];

    const int t = threadIdx.x;
    const int wid = t >> 6;
    const int l = t & 63;
    const int l15 = l & 15;
    const int l4 = l >> 4;
    const int wm = wid >> 1;
    const int wj = wid & 1;

    if (t < 128) {
        wv[t] = w_ws[(long)(m0 + t) * 8 + kb];
        mbs[t] = mblk[(long)(m0 + t) * 8 + kb];
    }

    f32x4 acc[4][8];
    #pragma unroll
    for (int m = 0; m < 4; ++m)
        #pragma unroll
        for (int nn = 0; nn < 8; ++nn)
            acc[m][nn] = (f32x4){0.f, 0.f, 0.f, 0.f};

    auto stage = [&](const unsigned short* Aptr, long lda,
                     const unsigned short* Bptr, long ldb, int k0) {
        #pragma unroll
        for (int s = 0; s < 4; ++s) {
            int ci = (wid * 4 + s) * 64 + l;
            int r = ci >> 3, cs = ci & 7;
            gload16(Aptr + (long)r * lda + k0 + ((cs ^ (r & 7)) << 3), &As[ci * 8]);
        }
        #pragma unroll
        for (int s = 0; s < 8; ++s) {
            int ci = (wid * 8 + s) * 64 + l;
            int rn = ci >> 3, cs = ci & 7;
            int sg = rn >> 6, jl = rn & 63;
            gload16(Bptr + (long)(sg * 256 + j0 + jl) * ldb + k0 + ((cs ^ (rn & 7)) << 3),
                    &Bs[ci * 8]);
        }
    };

    auto compute = [&]() {
        #pragma unroll
        for (int kh = 0; kh < 2; ++kh) {
            bf16x8 af[4];
            #pragma unroll
            for (int m = 0; m < 4; ++m) {
                int r = wm * 64 + m * 16 + l15;
                int c = kh * 4 + l4;
                af[m] = *reinterpret_cast<const bf16x8*>(&As[r * 64 + ((c ^ (r & 7)) << 3)]);
            }
            #pragma unroll
            for (int sg = 0; sg < 4; ++sg) {
                #pragma unroll
                for (int jf = 0; jf < 2; ++jf) {
                    int rn = sg * 64 + wj * 32 + jf * 16 + l15;
                    int c = kh * 4 + l4;
                    bf16x8 bf = *reinterpret_cast<const bf16x8*>(
                        &Bs[rn * 64 + ((c ^ (rn & 7)) << 3)]);
                    #pragma unroll
                    for (int m = 0; m < 4; ++m)
                        acc[m][sg * 2 + jf] = __builtin_amdgcn_mfma_f32_16x16x32_bf16(
                            af[m], bf, acc[m][sg * 2 + jf], 0, 0, 0);
                }
            }
        }
    };

    {
        const unsigned short* A1 = Ib + (long)m0 * 512;
        const unsigned short* B1 = Gt + (long)kb * 1024 * 512;
        for (int k0 = 0; k0 < 512; k0 += 64) {
            stage(A1, 512, B1, 512, k0);
            __syncthreads();
            compute();
            __syncthreads();
        }
    }

    {
        float wsc[4][4];
        #pragma unroll
        for (int m = 0; m < 4; ++m)
            #pragma unroll
            for (int r = 0; r < 4; ++r)
                wsc[m][r] = wv[wm * 64 + m * 16 + l4 * 4 + r];
        #pragma unroll
        for (int m = 0; m < 4; ++m)
            #pragma unroll
            for (int nn = 0; nn < 8; ++nn)
                #pragma unroll
                for (int r = 0; r < 4; ++r)
                    acc[m][nn][r] *= wsc[m][r];
    }

    {
        const unsigned short* A2 = Hb + (long)m0 * 2048 + kb * 256;
        const unsigned short* B2 = Whhb + (long)kb * 1024 * 256;
        for (int k0 = 0; k0 < 256; k0 += 64) {
            stage(A2, 2048, B2, 256, k0);
            __syncthreads();
            compute();
            __syncthreads();
        }
    }

    #pragma unroll
    for (int jf = 0; jf < 2; ++jf) {
        const int jcol = j0 + wj * 32 + jf * 16 + l15;
        const long bb = (long)kb * 1024 + jcol;
        const float bI = b_ih[bb] + b_hh[bb];
        const float bF = b_ih[bb + 256] + b_hh[bb + 256];
        const float bG = b_ih[bb + 512] + b_hh[bb + 512];
        const float bO = b_ih[bb + 768] + b_hh[bb + 768];
        #pragma unroll
        for (int m = 0; m < 4; ++m) {
            #pragma unroll
            for (int r = 0; r < 4; ++r) {
                const long row = m0 + wm * 64 + m * 16 + l4 * 4 + r;
                const long idx = row * 2048 + kb * 256 + jcol;
                const float mv = mbs[wm * 64 + m * 16 + l4 * 4 + r];
                const float ig = acc[m][0 + jf][r] + bI;
                const float fg = acc[m][2 + jf][r] + bF;
                const float gg = acc[m][4 + jf][r] + bG;
                const float og = acc[m][6 + jf][r] + bO;
                const float co = cx[idx];
                const float cn = sigf(fg) * co + sigf(ig) * tanhf(gg);
                const float hn = sigf(og) * tanhf(cn);
                c_out[idx] = (mv != 0.0f) ? cn : co;
                hn_b[idx] = f2bf(hn);
            }
        }
    }
}

// ---------------------------------------------------------------------------
// Inner NBxNB attention over bf16 qkv [4096][1536]; vectorized u16x8 loads.
// ---------------------------------------------------------------------------
__global__ __launch_bounds__(256) void attn_m2_kernel(
    const unsigned short* __restrict__ qkv, unsigned short* __restrict__ ob)
{
    const int tid = blockIdx.x * 256 + threadIdx.x;
    const int b = tid >> 5;
    const int qkb = (tid >> 2) & 7;
    const int h = tid & 3;
    const u16x8* base8 = reinterpret_cast<const u16x8*>(qkv + (long)b * 1536);

    float qv[16];
    {
        u16x8 q0 = base8[qkb * 24 + h * 2];
        u16x8 q1 = base8[qkb * 24 + h * 2 + 1];
        #pragma unroll
        for (int e = 0; e < 8; ++e) { qv[e] = bf2f(q0[e]); qv[8 + e] = bf2f(q1[e]); }
    }

    float sc[8];
    float mx = -1e30f;
    #pragma unroll
    for (int kk = 0; kk < 8; ++kk) {
        u16x8 k0 = base8[kk * 24 + 8 + h * 2];
        u16x8 k1 = base8[kk * 24 + 9 + h * 2];
        float s = 0.f;
        #pragma unroll
        for (int e = 0; e < 8; ++e)
            s += qv[e] * bf2f(k0[e]) + qv[8 + e] * bf2f(k1[e]);
        s *= 0.25f;
        sc[kk] = s;
        mx = fmaxf(mx, s);
    }
    float den = 0.f;
    #pragma unroll
    for (int kk = 0; kk < 8; ++kk) { sc[kk] = expf(sc[kk] - mx); den += sc[kk]; }
    const float inv = 1.0f / den;

    float ov[16] = {};
    #pragma unroll
    for (int kk = 0; kk < 8; ++kk) {
        const float pw = sc[kk] * inv;
        u16x8 v0 = base8[kk * 24 + 16 + h * 2];
        u16x8 v1 = base8[kk * 24 + 17 + h * 2];
        #pragma unroll
        for (int e = 0; e < 8; ++e) {
            ov[e] += pw * bf2f(v0[e]);
            ov[8 + e] += pw * bf2f(v1[e]);
        }
    }
    u16x8 r0, r1;
    #pragma unroll
    for (int e = 0; e < 8; ++e) { r0[e] = f2bf(ov[e]); r1[e] = f2bf(ov[e + 8]); }
    unsigned short* op = ob + (long)((b * 8 + qkb) * 64 + h * 16);
    *reinterpret_cast<u16x8*>(op) = r0;
    *reinterpret_cast<u16x8*>(op + 8) = r1;
}

// ---------------------------------------------------------------------------
// MFMA attn-final: g = O@gate_w^T, f = O@fc_w^T (K=64), att = sig(g)*tanh(f).
// h_final = bf2f(hnb) + att; masked blend vs hx. h_out is pure-write.
// ---------------------------------------------------------------------------
__global__ __launch_bounds__(256) void attn_final_kernel(
    const unsigned short* __restrict__ ob,   // [32768][64]
    const unsigned short* __restrict__ Wgfb, // [512][64]: 0-255 gate, 256-511 fc
    const float* __restrict__ gate_b, const float* __restrict__ fc_b,
    const float* __restrict__ mblk,
    const float* __restrict__ hx,
    const unsigned short* __restrict__ hnb,  // bf16 h_new [4096][2048]
    float* __restrict__ h_out)
{
    const int m0 = blockIdx.x * 128;
    const int j0 = blockIdx.y * 64;

    __shared__ unsigned short As[128 * 64];
    __shared__ unsigned short Bs[128 * 64];

    const int t = threadIdx.x;
    const int wid = t >> 6;
    const int l = t & 63;
    const int l15 = l & 15;
    const int l4 = l >> 4;
    const int wm = wid >> 1;
    const int wn = wid & 1;

    #pragma unroll
    for (int s = 0; s < 4; ++s) {
        int ci = (wid * 4 + s) * 64 + l;
        int r = ci >> 3, cs = ci & 7;
        gload16(ob + (long)(m0 + r) * 64 + ((cs ^ (r & 7)) << 3), &As[ci * 8]);
    }
    #pragma unroll
    for (int s = 0; s < 4; ++s) {
        int ci = (wid * 4 + s) * 64 + l;
        int r = ci >> 3, cs = ci & 7;
        int n = (r < 64) ? (j0 + r) : (256 + j0 + (r - 64));
        gload16(Wgfb + (long)n * 64 + ((cs ^ (r & 7)) << 3), &Bs[ci * 8]);
    }
    __syncthreads();

    f32x4 acc[4][2][2];
    #pragma unroll
    for (int m = 0; m < 4; ++m)
        #pragma unroll
        for (int nf = 0; nf < 2; ++nf)
            #pragma unroll
            for (int gf = 0; gf < 2; ++gf)
                acc[m][nf][gf] = (f32x4){0.f, 0.f, 0.f, 0.f};

    #pragma unroll
    for (int kh = 0; kh < 2; ++kh) {
        const int c = kh * 4 + l4;
        bf16x8 af[4];
        #pragma unroll
        for (int m = 0; m < 4; ++m) {
            int r = wm * 64 + m * 16 + l15;
            af[m] = *reinterpret_cast<const bf16x8*>(&As[r * 64 + ((c ^ (r & 7)) << 3)]);
        }
        #pragma unroll
        for (int nf = 0; nf < 2; ++nf) {
            int rg = wn * 32 + nf * 16 + l15;
            bf16x8 bg = *reinterpret_cast<const bf16x8*>(
                &Bs[rg * 64 + ((c ^ (rg & 7)) << 3)]);
            int rf = 64 + rg;
            bf16x8 bfv = *reinterpret_cast<const bf16x8*>(
                &Bs[rf * 64 + ((c ^ (rf & 7)) << 3)]);
            #pragma unroll
            for (int m = 0; m < 4; ++m) {
                acc[m][nf][0] = __builtin_amdgcn_mfma_f32_16x16x32_bf16(
                    af[m], bg, acc[m][nf][0], 0, 0, 0);
                acc[m][nf][1] = __builtin_amdgcn_mfma_f32_16x16x32_bf16(
                    af[m], bfv, acc[m][nf][1], 0, 0, 0);
            }
        }
    }

    #pragma unroll
    for (int nf = 0; nf < 2; ++nf) {
        const int j = j0 + wn * 32 + nf * 16 + l15;
        const float gb = gate_b[j];
        const float fb = fc_b[j];
        #pragma unroll
        for (int m = 0; m < 4; ++m) {
            #pragma unroll
            for (int r = 0; r < 4; ++r) {
                const long p = m0 + wm * 64 + m * 16 + l4 * 4 + r;
                const float g = acc[m][nf][0][r] + gb;
                const float f = acc[m][nf][1][r] + fb;
                const float att = sigf(g) * tanhf(f);
                const long idx = (p >> 3) * 2048 + (p & 7) * 256 + j;
                const float mv = mblk[p];
                const float hn = bf2f(hnb[idx]) + att;
                h_out[idx] = (mv != 0.0f) ? hn : hx[idx];
            }
        }
    }
}

// ---------------------------------------------------------------------------
extern "C" void kernel_launch(void* const* d_in, const int* in_sizes, int n_in,
                              void* d_out, int out_size, void* d_ws, size_t ws_size,
                              hipStream_t stream) {
    const float* inp    = (const float*)d_in[0];
    const float* hx     = (const float*)d_in[1];
    const float* cx     = (const float*)d_in[2];
    const float* Wq_i   = (const float*)d_in[3];
    const float* Wk_i   = (const float*)d_in[4];
    const float* Wv_i   = (const float*)d_in[5];
    const float* Wq_m   = (const float*)d_in[6];
    const float* Wk_m   = (const float*)d_in[7];
    const float* Wv_m   = (const float*)d_in[8];
    const float* fc_w   = (const float*)d_in[9];
    const float* fc_b   = (const float*)d_in[10];
    const float* gate_w = (const float*)d_in[11];
    const float* gate_b = (const float*)d_in[12];
    const float* Wih    = (const float*)d_in[13];
    const float* Whh    = (const float*)d_in[14];
    const float* b_ih   = (const float*)d_in[15];
    const float* b_hh   = (const float*)d_in[16];

    float* out      = (float*)d_out;
    float* h_out    = out;
    float* c_out    = out + (long)B_SZ * 2048;
    float* mask_out = out + (long)2 * B_SZ * 2048;

    // ---- workspace layout with lifetime aliasing (~61.1 MB) ----
    float* ws   = (float*)d_ws;
    float* w_ws = ws;                                       // B*8 f32
    float* mblk = w_ws + (long)B_SZ * 8;                    // B*8 f32
    unsigned short* Gt  = (unsigned short*)(mblk + (long)B_SZ * 8);  // 8*1024*512
    unsigned short* hxb = Gt + (long)8 * 1024 * 512;                 // B*2048
    unsigned short* hnb  = hxb + (long)B_SZ * 2048;         // B*2048 (gates -> final)
    unsigned short* Wihb = hnb + (long)B_SZ * 2048;         // 8M u16 (prepW -> G-gemm)
    unsigned short* Whhb = Wihb + (long)8 * 1024 * 1024;    // 2M u16 (prepW -> gates)
    unsigned short* Wgfb = Whhb + (long)8 * 1024 * 256;     // 512*64 u16
    unsigned short* Wqkvb = Wgfb + 512 * 64;                // 8*192*256 u16 (own slot)
    // early aliases inside Wihb span (dead before prepW):
    float* k1 = (float*)Wihb;                               // B*64 f32
    float* q  = k1 + (long)B_SZ * 64;                       // B*512 f32
    // Wvb: prep1 -> G-gemm; lives in hnb span (hnb written later by gates)
    unsigned short* Wvb = hnb;                              // 512*1024 bf16
    // inpb: prep1 -> gates; lives in d_out h region (attn_final overwrites all)
    unsigned short* inpb = (unsigned short*)h_out;          // B*512 bf16
    // late aliases (after gates):
    unsigned short* qkvb  = hxb;                            // B*1536 (over dead hxb)
    unsigned short* ob    = (unsigned short*)Gt;            // 32768*64 (over dead Gt)

    // fused prep: wgf | hx->bf16 | inp->bf16 | Wv1->bf16 | qkv-weight pack
    prep1_kernel<<<dim3(7040), 256, 0, stream>>>(
        gate_w, fc_w, Wgfb,
        (const float4*)hx, (u16x8*)hxb,
        (const float4*)inp, (u16x8*)inpb,
        (const float4*)(Wv_i + (long)NINP * ATT_OUT), (u16x8*)Wvb,
        Wq_m, Wk_m, Wv_m, Wqkvb);
    // k1 + q (f32, mask-critical)
    qk1_kernel<<<dim3(128, 9), 256, 0, stream>>>(
        inp, hx, Wk_i + (long)NINP * 64, Wq_i, k1, q);
    // s1, w, mblk, mask (kills k1,q)
    s1_mask_kernel<<<dim3(B_SZ / 4), 256, 0, stream>>>(q, k1, w_ws, mblk, mask_out);
    // fused Wih+Whh -> bf16 (clobbers k1/q aliases — dead)
    prepW_kernel<<<dim3(5120), 256, 0, stream>>>(
        (const float4*)Wih, (u16x8*)Wihb, (const float4*)Whh, (u16x8*)Whhb);
    // G[kb] = Wih[kb] @ Wv1^T  -> Gt [8][1024][512] bf16
    gemm_mfma_bf<<<dim3(8, 8, 8), 256, 0, stream>>>(
        Wihb, Wvb, Gt, 1024, 1024, 1024, 512,
        (long)1024 * 1024, 0, (long)1024 * 512);
    // gates + LSTM (R10 config)
    gates_mfma_kernel<<<dim3(B_SZ / 128, 4, 8), 256, 0, stream>>>(
        inpb, hxb, Gt, Whhb, b_ih, b_hh, w_ws, mblk, cx, c_out, hnb);
    // qkv = h_new_block @ W*_m (batched MFMA) -> bf16
    gemm_mfma_bf<<<dim3(32, 3, 8), 256, 0, stream>>>(
        hnb, Wqkvb, qkvb, 256, 2048, 256, 1536, 256, (long)192 * 256, 192);
    // inner attention -> ob (bf16)
    attn_m2_kernel<<<dim3(B_SZ * 32 / 256), 256, 0, stream>>>(qkvb, ob);
    // MFMA epilogue: att + h rebuild/blend (pure-write h_out, clobbers inpb)
    attn_final_kernel<<<dim3(256, 4), 256, 0, stream>>>(
        ob, Wgfb, gate_b, fc_b, mblk, hx, hnb, h_out);
}